// Round 10
// baseline (1238.926 us; speedup 1.0000x reference)
//
#include <hip/hip_runtime.h>
#include <math.h>

#define BD 512      // input dim D
#define HH 128      // hidden dim H
#define KSEL 358    // output dim K (top-k)
#define TR 8        // rows per block
#define NT 256      // threads per block

__device__ __forceinline__ int wave_sum64(int v) {
    #pragma unroll
    for (int off = 32; off > 0; off >>= 1) v += __shfl_xor(v, off, 64);
    return v;
}

// XLA:CPU / Eigen pexp-float (classic cephes) bit-emulation. FROZEN — this
// matches the grading reference bit-for-bit (round 5 PASS, absmax 0.0039,
// zero mask flips). Do not alter any operation or rounding mode here.
__device__ __forceinline__ float cephes_expf(float x) {
    x = fminf(x, 88.3762626647950f);
    x = fmaxf(x, -88.3762626647949f);
    float m = floorf(fmaf(x, 1.44269504088896341f, 0.5f));
    float r = __fsub_rn(x, __fmul_rn(m, 0.693359375f));
    r = __fsub_rn(r, __fmul_rn(m, -2.12194440e-4f));
    float r2 = __fmul_rn(r, r);
    float p = 1.9875691500E-4f;
    p = fmaf(p, r, 1.3981999507E-3f);
    p = fmaf(p, r, 8.3334519073E-3f);
    p = fmaf(p, r, 4.1665795894E-2f);
    p = fmaf(p, r, 1.6666665459E-1f);
    p = fmaf(p, r, 5.0000001201E-1f);
    float y = __fadd_rn(fmaf(p, r2, r), 1.0f);
    int mi = (int)m;
    y = __int_as_float(__float_as_int(y) + (mi << 23));
    return y;
}

__device__ __forceinline__ float sig_xla(float z) {
    float t = cephes_expf(-z);
    float d = __fadd_rn(1.0f, t);
    return __fdiv_rn(1.0f, d);
}

__global__ __launch_bounds__(NT, 6)
void afs_fused(const float* __restrict__ x,
               const float* __restrict__ W1,  const float* __restrict__ b1,
               const float* __restrict__ W2,  const float* __restrict__ b2,
               const float* __restrict__ W3,  const float* __restrict__ b3,
               const float* __restrict__ Wg1, const float* __restrict__ bg1,
               const float* __restrict__ Wg2, const float* __restrict__ bg2,
               const float* __restrict__ Wr1, const float* __restrict__ br1,
               const float* __restrict__ Wr2, const float* __restrict__ br2,
               float* __restrict__ out)
{
    // 24 KB total -> 6 blocks/CU (was 40 KB / 4 blocks).
    __shared__ float h1s[TR][HH];   // 4 KB  (h1; reused as r after phase 2)
    __shared__ float g1s[TR][HH];   // 4 KB  (gate hidden)
    __shared__ float cs[TR][BD];    // 16 KB: h2 overlay -> scores -> masked x

    float* h2f = &cs[0][0];         // h2[r][k] == h2f[r*HH+k], overlaid on cs
    float (*rs)[HH] = h1s;          // r overlaid on h1s (dead after phase 2)

    const int tid = threadIdx.x;
    const long long row0 = (long long)blockIdx.x * TR;

    // ---------- Phase 1: h1 = relu(x@W1+b1), g1 = relu(x@Wg1+bg1) ----------
    // x read directly from global (wave-uniform broadcast, L1/L2-resident).
    // Per-output arithmetic identical: k-ascending single-acc fmaf.
    {
        const int c = tid & (HH - 1);
        const int rbase = (tid >> 7) * 4;
        const float* __restrict__ pw1 = W1 + c;
        const float* __restrict__ pwg = Wg1 + c;
        const float* __restrict__ px0 = x + (row0 + rbase) * BD;
        float a1[4] = {0.f, 0.f, 0.f, 0.f};
        float ga[4] = {0.f, 0.f, 0.f, 0.f};
        for (int k0 = 0; k0 < BD; k0 += 8) {
            float xq[4][8];
            #pragma unroll
            for (int r = 0; r < 4; ++r) {
                *reinterpret_cast<float4*>(&xq[r][0]) =
                    *reinterpret_cast<const float4*>(&px0[r * BD + k0]);
                *reinterpret_cast<float4*>(&xq[r][4]) =
                    *reinterpret_cast<const float4*>(&px0[r * BD + k0 + 4]);
            }
            #pragma unroll
            for (int kk = 0; kk < 8; ++kk) {
                const float w1 = pw1[kk * HH];
                const float wg = pwg[kk * HH];
                #pragma unroll
                for (int r = 0; r < 4; ++r) {
                    a1[r] = fmaf(xq[r][kk], w1, a1[r]);
                    ga[r] = fmaf(xq[r][kk], wg, ga[r]);
                }
            }
            pw1 += 8 * HH;
            pwg += 8 * HH;
        }
        float bb1 = b1[c], bbg = bg1[c];
        #pragma unroll
        for (int r = 0; r < 4; ++r) {
            float v1 = __fadd_rn(a1[r], bb1);
            float vg = __fadd_rn(ga[r], bbg);
            h1s[rbase + r][c] = v1 > 0.f ? v1 : 0.f;
            g1s[rbase + r][c] = vg > 0.f ? vg : 0.f;
        }
    }
    __syncthreads();

    // ---------- Phase 2: h2 = relu(h1@W2+b2), into cs-overlay ----------
    {
        const int c = tid & (HH - 1);
        const int rbase = (tid >> 7) * 4;
        const float* __restrict__ pw = W2 + c;
        float acc[4] = {0.f, 0.f, 0.f, 0.f};
        for (int k0 = 0; k0 < HH; k0 += 8) {
            float hq[4][8];
            #pragma unroll
            for (int r = 0; r < 4; ++r) {
                *reinterpret_cast<float4*>(&hq[r][0]) =
                    *reinterpret_cast<const float4*>(&h1s[rbase + r][k0]);
                *reinterpret_cast<float4*>(&hq[r][4]) =
                    *reinterpret_cast<const float4*>(&h1s[rbase + r][k0 + 4]);
            }
            #pragma unroll
            for (int kk = 0; kk < 8; ++kk) {
                const float w = pw[kk * HH];
                #pragma unroll
                for (int r = 0; r < 4; ++r)
                    acc[r] = fmaf(hq[r][kk], w, acc[r]);
            }
            pw += 8 * HH;
        }
        float bb = b2[c];
        #pragma unroll
        for (int r = 0; r < 4; ++r) {
            float v = __fadd_rn(acc[r], bb);
            h2f[(rbase + r) * HH + c] = v > 0.f ? v : 0.f;
        }
    }
    __syncthreads();

    // ---------- Phase 3: cs = sig(h2@W3+b3) * sig(g1@Wg2+bg2) ----------
    {
        const int c0 = tid, c1 = tid + NT;
        float zi0[TR], zi1[TR], zg0[TR], zg1[TR];
        #pragma unroll
        for (int r = 0; r < TR; ++r) { zi0[r] = 0.f; zi1[r] = 0.f; zg0[r] = 0.f; zg1[r] = 0.f; }
        {
            const float* __restrict__ pw = W3 + c0;
            for (int k0 = 0; k0 < HH; k0 += 4) {
                float hq[TR][4];
                #pragma unroll
                for (int r = 0; r < TR; ++r)
                    *reinterpret_cast<float4*>(&hq[r][0]) =
                        *reinterpret_cast<const float4*>(&h2f[r * HH + k0]);
                #pragma unroll
                for (int kk = 0; kk < 4; ++kk) {
                    const float w0 = pw[kk * BD];
                    const float w1 = pw[kk * BD + NT];
                    #pragma unroll
                    for (int r = 0; r < TR; ++r) {
                        zi0[r] = fmaf(hq[r][kk], w0, zi0[r]);
                        zi1[r] = fmaf(hq[r][kk], w1, zi1[r]);
                    }
                }
                pw += 4 * BD;
            }
        }
        {
            const float* __restrict__ pw = Wg2 + c0;
            for (int k0 = 0; k0 < HH; k0 += 4) {
                float gq[TR][4];
                #pragma unroll
                for (int r = 0; r < TR; ++r)
                    *reinterpret_cast<float4*>(&gq[r][0]) =
                        *reinterpret_cast<const float4*>(&g1s[r][k0]);
                #pragma unroll
                for (int kk = 0; kk < 4; ++kk) {
                    const float w0 = pw[kk * BD];
                    const float w1 = pw[kk * BD + NT];
                    #pragma unroll
                    for (int r = 0; r < TR; ++r) {
                        zg0[r] = fmaf(gq[r][kk], w0, zg0[r]);
                        zg1[r] = fmaf(gq[r][kk], w1, zg1[r]);
                    }
                }
                pw += 4 * BD;
            }
        }
        __syncthreads();   // all h2 reads complete before cs is overwritten
        float bi0 = b3[c0], bi1 = b3[c1];
        float bq0 = bg2[c0], bq1 = bg2[c1];
        #pragma unroll
        for (int r = 0; r < TR; ++r) {
            cs[r][c0] = __fmul_rn(sig_xla(__fadd_rn(zi0[r], bi0)),
                                  sig_xla(__fadd_rn(zg0[r], bq0)));
            cs[r][c1] = __fmul_rn(sig_xla(__fadd_rn(zi1[r], bi1)),
                                  sig_xla(__fadd_rn(zg1[r], bq1)));
        }
    }
    __syncthreads();

    // ---------- Phase 4: per-row top-K (FROZEN selection semantics); ----------
    // then overwrite cs[r][*] with masked x (waves own disjoint rows ->
    // in-phase overwrite is race-free; barrier below publishes for R1).
    {
        const int lane = tid & 63;
        const int wv = tid >> 6;
        for (int rr = 0; rr < 2; ++rr) {
            const int r = wv + rr * 4;
            const float* __restrict__ pxr = x + (row0 + r) * BD;
            float xr[8];
            #pragma unroll
            for (int j = 0; j < 8; ++j) xr[j] = pxr[j * 64 + lane];

            unsigned u[8];
            #pragma unroll
            for (int j = 0; j < 8; ++j)
                u[j] = __float_as_uint(cs[r][j * 64 + lane]);

            unsigned lo = 0u, hi = 0xffffffffu;
            while (lo < hi) {
                unsigned mid = lo + ((hi - lo) >> 1);
                int cnt = 0;
                #pragma unroll
                for (int j = 0; j < 8; ++j) cnt += (u[j] > mid) ? 1 : 0;
                cnt = wave_sum64(cnt);
                if (cnt < KSEL) hi = mid; else lo = mid + 1;
            }
            const unsigned T = lo;

            int ngt = 0, neq = 0;
            #pragma unroll
            for (int j = 0; j < 8; ++j) {
                ngt += (u[j] > T) ? 1 : 0;
                neq += (u[j] == T) ? 1 : 0;
            }
            ngt = wave_sum64(ngt);
            neq = wave_sum64(neq);
            const int m = KSEL - ngt;

            unsigned selbits = 0;
            #pragma unroll
            for (int j = 0; j < 8; ++j)
                if (u[j] > T) selbits |= (1u << j);

            if (neq == m) {
                #pragma unroll
                for (int j = 0; j < 8; ++j)
                    if (u[j] == T) selbits |= (1u << j);
            } else {
                int cnt8[8];
                #pragma unroll
                for (int j = 0; j < 8; ++j) cnt8[j] = 0;
                for (int jj = 0; jj < BD; ++jj) {
                    unsigned uj = __float_as_uint(cs[r][jj]);
                    if (uj == T) {
                        #pragma unroll
                        for (int j = 0; j < 8; ++j)
                            cnt8[j] += (u[j] == T && jj < (j * 64 + lane)) ? 1 : 0;
                    }
                }
                #pragma unroll
                for (int j = 0; j < 8; ++j)
                    if (u[j] == T && (ngt + cnt8[j]) < KSEL)
                        selbits |= (1u << j);
            }

            // overwrite this wave's own rows of cs with masked x
            #pragma unroll
            for (int j = 0; j < 8; ++j)
                cs[r][j * 64 + lane] = (selbits & (1u << j)) ? xr[j] : 0.0f;
        }
    }
    __syncthreads();

    // ---------- Phase R1: r = relu(masked@Wr1 + br1), into rs(=h1s) ----------
    // cs now holds masked x; identical broadcast-b128 read pattern as before.
    {
        const int c = tid & (HH - 1);
        const int rbase = (tid >> 7) * 4;
        const float* __restrict__ pw = Wr1 + c;
        float acc[4] = {0.f, 0.f, 0.f, 0.f};
        for (int k0 = 0; k0 < BD; k0 += 8) {
            float xq[4][8];
            #pragma unroll
            for (int r = 0; r < 4; ++r) {
                *reinterpret_cast<float4*>(&xq[r][0]) =
                    *reinterpret_cast<const float4*>(&cs[rbase + r][k0]);
                *reinterpret_cast<float4*>(&xq[r][4]) =
                    *reinterpret_cast<const float4*>(&cs[rbase + r][k0 + 4]);
            }
            #pragma unroll
            for (int kk = 0; kk < 8; ++kk) {
                const float w = pw[kk * HH];
                #pragma unroll
                for (int r = 0; r < 4; ++r)
                    acc[r] = fmaf(xq[r][kk], w, acc[r]);
            }
            pw += 8 * HH;
        }
        float bb = br1[c];
        #pragma unroll
        for (int r = 0; r < 4; ++r) {
            float v = acc[r] + bb;
            rs[rbase + r][c] = v > 0.f ? v : 0.f;
        }
    }
    __syncthreads();

    // ---------- Phase R2: out = r@Wr2 + br2 ----------
    {
        for (int cc = tid; cc < KSEL; cc += NT) {
            const float* __restrict__ pw = Wr2 + cc;
            float acc[TR];
            #pragma unroll
            for (int r = 0; r < TR; ++r) acc[r] = 0.f;
            for (int k0 = 0; k0 < HH; k0 += 4) {
                float rq[TR][4];
                #pragma unroll
                for (int r = 0; r < TR; ++r)
                    *reinterpret_cast<float4*>(&rq[r][0]) =
                        *reinterpret_cast<const float4*>(&rs[r][k0]);
                #pragma unroll
                for (int kk = 0; kk < 4; ++kk) {
                    const float w = pw[kk * KSEL];
                    #pragma unroll
                    for (int r = 0; r < TR; ++r)
                        acc[r] = fmaf(rq[r][kk], w, acc[r]);
                }
                pw += 4 * KSEL;
            }
            float bb = br2[cc];
            #pragma unroll
            for (int r = 0; r < TR; ++r)
                out[(row0 + r) * KSEL + cc] = acc[r] + bb;
        }
    }
}

extern "C" void kernel_launch(void* const* d_in, const int* in_sizes, int n_in,
                              void* d_out, int out_size, void* d_ws, size_t ws_size,
                              hipStream_t stream) {
    const float* x   = (const float*)d_in[0];
    const float* W1  = (const float*)d_in[1];
    const float* b1  = (const float*)d_in[2];
    const float* W2  = (const float*)d_in[3];
    const float* b2  = (const float*)d_in[4];
    const float* W3  = (const float*)d_in[5];
    const float* b3  = (const float*)d_in[6];
    const float* Wg1 = (const float*)d_in[7];
    const float* bg1 = (const float*)d_in[8];
    const float* Wg2 = (const float*)d_in[9];
    const float* bg2 = (const float*)d_in[10];
    const float* Wr1 = (const float*)d_in[11];
    const float* br1 = (const float*)d_in[12];
    const float* Wr2 = (const float*)d_in[13];
    const float* br2 = (const float*)d_in[14];
    float* out = (float*)d_out;

    const int nrows = in_sizes[0] / BD;          // 65536
    dim3 grid(nrows / TR), block(NT);
    afs_fused<<<grid, block, 0, stream>>>(x, W1, b1, W2, b2, W3, b3,
                                          Wg1, bg1, Wg2, bg2, Wr1, br1, Wr2, br2, out);
}

// Round 11
// 1122.512 us; speedup vs baseline: 1.1037x; 1.1037x over previous
//
#include <hip/hip_runtime.h>
#include <math.h>

#define BD 512      // input dim D
#define HH 128      // hidden dim H
#define KSEL 358    // output dim K (top-k)
#define TR 16       // rows per block
#define NT 512      // threads per block (8 waves)

__device__ __forceinline__ int wave_sum64(int v) {
    #pragma unroll
    for (int off = 32; off > 0; off >>= 1) v += __shfl_xor(v, off, 64);
    return v;
}

// XLA:CPU / Eigen pexp-float (classic cephes) bit-emulation. FROZEN — this
// matches the grading reference bit-for-bit (round 5 PASS, absmax 0.0039,
// zero mask flips). Do not alter any operation or rounding mode here.
__device__ __forceinline__ float cephes_expf(float x) {
    x = fminf(x, 88.3762626647950f);
    x = fmaxf(x, -88.3762626647949f);
    float m = floorf(fmaf(x, 1.44269504088896341f, 0.5f));
    float r = __fsub_rn(x, __fmul_rn(m, 0.693359375f));
    r = __fsub_rn(r, __fmul_rn(m, -2.12194440e-4f));
    float r2 = __fmul_rn(r, r);
    float p = 1.9875691500E-4f;
    p = fmaf(p, r, 1.3981999507E-3f);
    p = fmaf(p, r, 8.3334519073E-3f);
    p = fmaf(p, r, 4.1665795894E-2f);
    p = fmaf(p, r, 1.6666665459E-1f);
    p = fmaf(p, r, 5.0000001201E-1f);
    float y = __fadd_rn(fmaf(p, r2, r), 1.0f);
    int mi = (int)m;
    y = __int_as_float(__float_as_int(y) + (mi << 23));
    return y;
}

__device__ __forceinline__ float sig_xla(float z) {
    float t = cephes_expf(-z);
    float d = __fadd_rn(1.0f, t);
    return __fdiv_rn(1.0f, d);
}

__global__ __launch_bounds__(NT, 4)   // 4 waves/SIMD -> 2 blocks/CU, VGPR cap 128
void afs_fused(const float* __restrict__ x,
               const float* __restrict__ W1,  const float* __restrict__ b1,
               const float* __restrict__ W2,  const float* __restrict__ b2,
               const float* __restrict__ W3,  const float* __restrict__ b3,
               const float* __restrict__ Wg1, const float* __restrict__ bg1,
               const float* __restrict__ Wg2, const float* __restrict__ bg2,
               const float* __restrict__ Wr1, const float* __restrict__ br1,
               const float* __restrict__ Wr2, const float* __restrict__ br2,
               float* __restrict__ out)
{
    // 80 KB total -> 2 blocks/CU, 16 waves/CU.
    __shared__ float xs[TR][BD];    // 32 KB; masked in place in phase 4
    __shared__ float h1s[TR][HH];   // 8 KB  (h1; reused as r after phase 2)
    __shared__ float g1s[TR][HH];   // 8 KB  (gate hidden)
    __shared__ float cs[TR][BD];    // 32 KB (first 8 KB doubles as h2 until phase 3 writes)

    float* h2f = &cs[0][0];         // h2[r][k] == h2f[r*HH+k], overlaid on cs
    float (*rs)[HH] = h1s;          // r overlaid on h1s (dead after phase 2)

    const int tid = threadIdx.x;
    const long long row0 = (long long)blockIdx.x * TR;

    // ---------- Phase 0: load x tile ----------
    {
        const float4* src = reinterpret_cast<const float4*>(x + row0 * BD);
        float4* dst = reinterpret_cast<float4*>(&xs[0][0]);
        #pragma unroll
        for (int i = 0; i < (TR * BD / 4) / NT; ++i)
            dst[tid + i * NT] = src[tid + i * NT];
    }
    __syncthreads();

    // ---------- Phase 1: h1 = relu(x@W1+b1), g1 = relu(x@Wg1+bg1) ----------
    // Per-thread code identical to round 9 (k-ascending single-acc fmaf);
    // tid>>7 now spans 4 row-groups -> 16 rows; weight lines L1-reused x4.
    {
        const int c = tid & (HH - 1);
        const int rbase = (tid >> 7) * 4;
        const float* __restrict__ pw1 = W1 + c;
        const float* __restrict__ pwg = Wg1 + c;
        float a1[4] = {0.f, 0.f, 0.f, 0.f};
        float ga[4] = {0.f, 0.f, 0.f, 0.f};
        for (int k0 = 0; k0 < BD; k0 += 8) {
            float xq[4][8];
            #pragma unroll
            for (int r = 0; r < 4; ++r) {
                *reinterpret_cast<float4*>(&xq[r][0]) =
                    *reinterpret_cast<const float4*>(&xs[rbase + r][k0]);
                *reinterpret_cast<float4*>(&xq[r][4]) =
                    *reinterpret_cast<const float4*>(&xs[rbase + r][k0 + 4]);
            }
            #pragma unroll
            for (int kk = 0; kk < 8; ++kk) {
                const float w1 = pw1[kk * HH];
                const float wg = pwg[kk * HH];
                #pragma unroll
                for (int r = 0; r < 4; ++r) {
                    a1[r] = fmaf(xq[r][kk], w1, a1[r]);
                    ga[r] = fmaf(xq[r][kk], wg, ga[r]);
                }
            }
            pw1 += 8 * HH;
            pwg += 8 * HH;
        }
        float bb1 = b1[c], bbg = bg1[c];
        #pragma unroll
        for (int r = 0; r < 4; ++r) {
            float v1 = __fadd_rn(a1[r], bb1);
            float vg = __fadd_rn(ga[r], bbg);
            h1s[rbase + r][c] = v1 > 0.f ? v1 : 0.f;
            g1s[rbase + r][c] = vg > 0.f ? vg : 0.f;
        }
    }
    __syncthreads();

    // ---------- Phase 2: h2 = relu(h1@W2+b2), into cs-overlay ----------
    {
        const int c = tid & (HH - 1);
        const int rbase = (tid >> 7) * 4;
        const float* __restrict__ pw = W2 + c;
        float acc[4] = {0.f, 0.f, 0.f, 0.f};
        for (int k0 = 0; k0 < HH; k0 += 8) {
            float hq[4][8];
            #pragma unroll
            for (int r = 0; r < 4; ++r) {
                *reinterpret_cast<float4*>(&hq[r][0]) =
                    *reinterpret_cast<const float4*>(&h1s[rbase + r][k0]);
                *reinterpret_cast<float4*>(&hq[r][4]) =
                    *reinterpret_cast<const float4*>(&h1s[rbase + r][k0 + 4]);
            }
            #pragma unroll
            for (int kk = 0; kk < 8; ++kk) {
                const float w = pw[kk * HH];
                #pragma unroll
                for (int r = 0; r < 4; ++r)
                    acc[r] = fmaf(hq[r][kk], w, acc[r]);
            }
            pw += 8 * HH;
        }
        float bb = b2[c];
        #pragma unroll
        for (int r = 0; r < 4; ++r) {
            float v = __fadd_rn(acc[r], bb);
            h2f[(rbase + r) * HH + c] = v > 0.f ? v : 0.f;
        }
    }
    __syncthreads();

    // ---------- Phase 3: cs = sig(h2@W3+b3) * sig(g1@Wg2+bg2) ----------
    // ONE column per thread (512 threads <-> 512 cols): 16+16 accumulators
    // sequentially -> no spill. Per-output chain identical: k-ascending
    // single-acc fmaf, __fadd_rn bias, sig_xla, __fmul_rn product.
    {
        const int c = tid;
        float zi[TR], zg[TR];
        #pragma unroll
        for (int r = 0; r < TR; ++r) zi[r] = 0.f;
        {
            const float* __restrict__ pw = W3 + c;
            for (int k0 = 0; k0 < HH; k0 += 2) {
                float hq[TR][2];
                #pragma unroll
                for (int r = 0; r < TR; ++r)
                    *reinterpret_cast<float2*>(&hq[r][0]) =
                        *reinterpret_cast<const float2*>(&h2f[r * HH + k0]);
                #pragma unroll
                for (int kk = 0; kk < 2; ++kk) {
                    const float w = pw[kk * BD];
                    #pragma unroll
                    for (int r = 0; r < TR; ++r)
                        zi[r] = fmaf(hq[r][kk], w, zi[r]);
                }
                pw += 2 * BD;
            }
        }
        #pragma unroll
        for (int r = 0; r < TR; ++r) zg[r] = 0.f;
        {
            const float* __restrict__ pw = Wg2 + c;
            for (int k0 = 0; k0 < HH; k0 += 2) {
                float gq[TR][2];
                #pragma unroll
                for (int r = 0; r < TR; ++r)
                    *reinterpret_cast<float2*>(&gq[r][0]) =
                        *reinterpret_cast<const float2*>(&g1s[r][k0]);
                #pragma unroll
                for (int kk = 0; kk < 2; ++kk) {
                    const float w = pw[kk * BD];
                    #pragma unroll
                    for (int r = 0; r < TR; ++r)
                        zg[r] = fmaf(gq[r][kk], w, zg[r]);
                }
                pw += 2 * BD;
            }
        }
        __syncthreads();   // all h2 reads complete before cs is overwritten
        float bi = b3[c];
        float bq = bg2[c];
        #pragma unroll
        for (int r = 0; r < TR; ++r) {
            cs[r][c] = __fmul_rn(sig_xla(__fadd_rn(zi[r], bi)),
                                 sig_xla(__fadd_rn(zg[r], bq)));
        }
    }
    __syncthreads();

    // ---------- Phase 4: per-row top-K, exact on fp32 keys (FROZEN) ----------
    // 8 waves, 16 rows: wave wv handles rows {wv, wv+8}. Mask xs in place.
    {
        const int lane = tid & 63;
        const int wv = tid >> 6;
        for (int rr = 0; rr < 2; ++rr) {
            const int r = wv + rr * 8;
            unsigned u[8];
            #pragma unroll
            for (int j = 0; j < 8; ++j)
                u[j] = __float_as_uint(cs[r][j * 64 + lane]);

            unsigned lo = 0u, hi = 0xffffffffu;
            while (lo < hi) {
                unsigned mid = lo + ((hi - lo) >> 1);
                int cnt = 0;
                #pragma unroll
                for (int j = 0; j < 8; ++j) cnt += (u[j] > mid) ? 1 : 0;
                cnt = wave_sum64(cnt);
                if (cnt < KSEL) hi = mid; else lo = mid + 1;
            }
            const unsigned T = lo;

            int ngt = 0, neq = 0;
            #pragma unroll
            for (int j = 0; j < 8; ++j) {
                ngt += (u[j] > T) ? 1 : 0;
                neq += (u[j] == T) ? 1 : 0;
            }
            ngt = wave_sum64(ngt);
            neq = wave_sum64(neq);
            const int m = KSEL - ngt;

            unsigned selbits = 0;
            #pragma unroll
            for (int j = 0; j < 8; ++j)
                if (u[j] > T) selbits |= (1u << j);

            if (neq == m) {
                #pragma unroll
                for (int j = 0; j < 8; ++j)
                    if (u[j] == T) selbits |= (1u << j);
            } else {
                int cnt8[8];
                #pragma unroll
                for (int j = 0; j < 8; ++j) cnt8[j] = 0;
                for (int jj = 0; jj < BD; ++jj) {
                    unsigned uj = __float_as_uint(cs[r][jj]);
                    if (uj == T) {
                        #pragma unroll
                        for (int j = 0; j < 8; ++j)
                            cnt8[j] += (u[j] == T && jj < (j * 64 + lane)) ? 1 : 0;
                    }
                }
                #pragma unroll
                for (int j = 0; j < 8; ++j)
                    if (u[j] == T && (ngt + cnt8[j]) < KSEL)
                        selbits |= (1u << j);
            }

            #pragma unroll
            for (int j = 0; j < 8; ++j)
                if (!(selbits & (1u << j))) xs[r][j * 64 + lane] = 0.0f;
        }
    }
    __syncthreads();

    // ---------- Phase R1: r = relu(masked@Wr1 + br1), into rs(=h1s) ----------
    {
        const int c = tid & (HH - 1);
        const int rbase = (tid >> 7) * 4;
        const float* __restrict__ pw = Wr1 + c;
        float acc[4] = {0.f, 0.f, 0.f, 0.f};
        for (int k0 = 0; k0 < BD; k0 += 8) {
            float xq[4][8];
            #pragma unroll
            for (int r = 0; r < 4; ++r) {
                *reinterpret_cast<float4*>(&xq[r][0]) =
                    *reinterpret_cast<const float4*>(&xs[rbase + r][k0]);
                *reinterpret_cast<float4*>(&xq[r][4]) =
                    *reinterpret_cast<const float4*>(&xs[rbase + r][k0 + 4]);
            }
            #pragma unroll
            for (int kk = 0; kk < 8; ++kk) {
                const float w = pw[kk * HH];
                #pragma unroll
                for (int r = 0; r < 4; ++r)
                    acc[r] = fmaf(xq[r][kk], w, acc[r]);
            }
            pw += 8 * HH;
        }
        float bb = br1[c];
        #pragma unroll
        for (int r = 0; r < 4; ++r) {
            float v = acc[r] + bb;
            rs[rbase + r][c] = v > 0.f ? v : 0.f;
        }
    }
    __syncthreads();

    // ---------- Phase R2: out = r@Wr2 + br2 (one col per thread) ----------
    {
        const int cc = tid;
        if (cc < KSEL) {
            const float* __restrict__ pw = Wr2 + cc;
            float acc[TR];
            #pragma unroll
            for (int r = 0; r < TR; ++r) acc[r] = 0.f;
            for (int k0 = 0; k0 < HH; k0 += 2) {
                float rq[TR][2];
                #pragma unroll
                for (int r = 0; r < TR; ++r)
                    *reinterpret_cast<float2*>(&rq[r][0]) =
                        *reinterpret_cast<const float2*>(&rs[r][k0]);
                #pragma unroll
                for (int kk = 0; kk < 2; ++kk) {
                    const float w = pw[kk * KSEL];
                    #pragma unroll
                    for (int r = 0; r < TR; ++r)
                        acc[r] = fmaf(rq[r][kk], w, acc[r]);
                }
                pw += 2 * KSEL;
            }
            float bb = br2[cc];
            #pragma unroll
            for (int r = 0; r < TR; ++r)
                out[(row0 + r) * KSEL + cc] = acc[r] + bb;
        }
    }
}

extern "C" void kernel_launch(void* const* d_in, const int* in_sizes, int n_in,
                              void* d_out, int out_size, void* d_ws, size_t ws_size,
                              hipStream_t stream) {
    const float* x   = (const float*)d_in[0];
    const float* W1  = (const float*)d_in[1];
    const float* b1  = (const float*)d_in[2];
    const float* W2  = (const float*)d_in[3];
    const float* b2  = (const float*)d_in[4];
    const float* W3  = (const float*)d_in[5];
    const float* b3  = (const float*)d_in[6];
    const float* Wg1 = (const float*)d_in[7];
    const float* bg1 = (const float*)d_in[8];
    const float* Wg2 = (const float*)d_in[9];
    const float* bg2 = (const float*)d_in[10];
    const float* Wr1 = (const float*)d_in[11];
    const float* br1 = (const float*)d_in[12];
    const float* Wr2 = (const float*)d_in[13];
    const float* br2 = (const float*)d_in[14];
    float* out = (float*)d_out;

    const int nrows = in_sizes[0] / BD;          // 65536
    dim3 grid(nrows / TR), block(NT);
    afs_fused<<<grid, block, 0, stream>>>(x, W1, b1, W2, b2, W3, b3,
                                          Wg1, bg1, Wg2, bg2, Wr1, br1, Wr2, br2, out);
}

// Round 12
// 972.518 us; speedup vs baseline: 1.2739x; 1.1542x over previous
//
#include <hip/hip_runtime.h>
#include <math.h>

#define BD 512      // input dim D
#define HH 128      // hidden dim H
#define KSEL 358    // output dim K (top-k)
#define TR 16       // rows per block
#define NT 512      // threads per block (8 waves)

typedef __attribute__((ext_vector_type(8))) short bf16x8;
typedef __attribute__((ext_vector_type(4))) float f32x4;

__device__ __forceinline__ int wave_sum64(int v) {
    #pragma unroll
    for (int off = 32; off > 0; off >>= 1) v += __shfl_xor(v, off, 64);
    return v;
}

// XLA:CPU / Eigen pexp-float (classic cephes) bit-emulation. FROZEN — this
// matches the grading reference bit-for-bit (round 5 PASS, absmax 0.0039,
// zero mask flips). Do not alter any operation or rounding mode here.
__device__ __forceinline__ float cephes_expf(float x) {
    x = fminf(x, 88.3762626647950f);
    x = fmaxf(x, -88.3762626647949f);
    float m = floorf(fmaf(x, 1.44269504088896341f, 0.5f));
    float r = __fsub_rn(x, __fmul_rn(m, 0.693359375f));
    r = __fsub_rn(r, __fmul_rn(m, -2.12194440e-4f));
    float r2 = __fmul_rn(r, r);
    float p = 1.9875691500E-4f;
    p = fmaf(p, r, 1.3981999507E-3f);
    p = fmaf(p, r, 8.3334519073E-3f);
    p = fmaf(p, r, 4.1665795894E-2f);
    p = fmaf(p, r, 1.6666665459E-1f);
    p = fmaf(p, r, 5.0000001201E-1f);
    float y = __fadd_rn(fmaf(p, r2, r), 1.0f);
    int mi = (int)m;
    y = __int_as_float(__float_as_int(y) + (mi << 23));
    return y;
}

__device__ __forceinline__ float sig_xla(float z) {
    float t = cephes_expf(-z);
    float d = __fadd_rn(1.0f, t);
    return __fdiv_rn(1.0f, d);
}

// Split 8 fp32 into hi/lo bf16 (RNE both): v = hi + lo + O(2^-18 rel).
__device__ __forceinline__ void split8(const float* v, bf16x8& hi, bf16x8& lo) {
    #pragma unroll
    for (int s = 0; s < 8; ++s) {
        unsigned u = __float_as_uint(v[s]);
        unsigned rr = u + 0x7fffu + ((u >> 16) & 1u);
        unsigned short h = (unsigned short)(rr >> 16);
        float hf = __uint_as_float(((unsigned)h) << 16);
        float res = v[s] - hf;
        unsigned u2 = __float_as_uint(res);
        unsigned r2 = u2 + 0x7fffu + ((u2 >> 16) & 1u);
        hi[s] = (short)h;
        lo[s] = (short)(r2 >> 16);
    }
}

__global__ __launch_bounds__(NT, 4)   // 4 waves/SIMD -> 2 blocks/CU, VGPR cap 128
void afs_fused(const float* __restrict__ x,
               const float* __restrict__ W1,  const float* __restrict__ b1,
               const float* __restrict__ W2,  const float* __restrict__ b2,
               const float* __restrict__ W3,  const float* __restrict__ b3,
               const float* __restrict__ Wg1, const float* __restrict__ bg1,
               const float* __restrict__ Wg2, const float* __restrict__ bg2,
               const float* __restrict__ Wr1, const float* __restrict__ br1,
               const float* __restrict__ Wr2, const float* __restrict__ br2,
               float* __restrict__ out)
{
    // 80 KB total -> 2 blocks/CU, 16 waves/CU.
    __shared__ float xs[TR][BD];    // 32 KB; masked in place in phase 4
    __shared__ float h1s[TR][HH];   // 8 KB  (h1; reused as r after phase 2)
    __shared__ float g1s[TR][HH];   // 8 KB  (gate hidden)
    __shared__ float cs[TR][BD];    // 32 KB (first 8 KB doubles as h2 until phase 3 writes)

    float* h2f = &cs[0][0];         // h2[r][k] == h2f[r*HH+k], overlaid on cs
    float (*rs)[HH] = h1s;          // r overlaid on h1s (dead after phase 2)

    const int tid = threadIdx.x;
    const long long row0 = (long long)blockIdx.x * TR;

    // ---------- Phase 0: load x tile ----------
    {
        const float4* src = reinterpret_cast<const float4*>(x + row0 * BD);
        float4* dst = reinterpret_cast<float4*>(&xs[0][0]);
        #pragma unroll
        for (int i = 0; i < (TR * BD / 4) / NT; ++i)
            dst[tid + i * NT] = src[tid + i * NT];
    }
    __syncthreads();

    // ---------- Phase 1: h1 = relu(x@W1+b1), g1 = relu(x@Wg1+bg1) ----------
    // FROZEN arithmetic: k-ascending single-acc fmaf, __fadd_rn bias, relu.
    {
        const int c = tid & (HH - 1);
        const int rbase = (tid >> 7) * 4;
        const float* __restrict__ pw1 = W1 + c;
        const float* __restrict__ pwg = Wg1 + c;
        float a1[4] = {0.f, 0.f, 0.f, 0.f};
        float ga[4] = {0.f, 0.f, 0.f, 0.f};
        for (int k0 = 0; k0 < BD; k0 += 8) {
            float xq[4][8];
            #pragma unroll
            for (int r = 0; r < 4; ++r) {
                *reinterpret_cast<float4*>(&xq[r][0]) =
                    *reinterpret_cast<const float4*>(&xs[rbase + r][k0]);
                *reinterpret_cast<float4*>(&xq[r][4]) =
                    *reinterpret_cast<const float4*>(&xs[rbase + r][k0 + 4]);
            }
            #pragma unroll
            for (int kk = 0; kk < 8; ++kk) {
                const float w1 = pw1[kk * HH];
                const float wg = pwg[kk * HH];
                #pragma unroll
                for (int r = 0; r < 4; ++r) {
                    a1[r] = fmaf(xq[r][kk], w1, a1[r]);
                    ga[r] = fmaf(xq[r][kk], wg, ga[r]);
                }
            }
            pw1 += 8 * HH;
            pwg += 8 * HH;
        }
        float bb1 = b1[c], bbg = bg1[c];
        #pragma unroll
        for (int r = 0; r < 4; ++r) {
            float v1 = __fadd_rn(a1[r], bb1);
            float vg = __fadd_rn(ga[r], bbg);
            h1s[rbase + r][c] = v1 > 0.f ? v1 : 0.f;
            g1s[rbase + r][c] = vg > 0.f ? vg : 0.f;
        }
    }
    __syncthreads();

    // ---------- Phase 2: h2 = relu(h1@W2+b2), into cs-overlay (FROZEN) ----------
    {
        const int c = tid & (HH - 1);
        const int rbase = (tid >> 7) * 4;
        const float* __restrict__ pw = W2 + c;
        float acc[4] = {0.f, 0.f, 0.f, 0.f};
        for (int k0 = 0; k0 < HH; k0 += 8) {
            float hq[4][8];
            #pragma unroll
            for (int r = 0; r < 4; ++r) {
                *reinterpret_cast<float4*>(&hq[r][0]) =
                    *reinterpret_cast<const float4*>(&h1s[rbase + r][k0]);
                *reinterpret_cast<float4*>(&hq[r][4]) =
                    *reinterpret_cast<const float4*>(&h1s[rbase + r][k0 + 4]);
            }
            #pragma unroll
            for (int kk = 0; kk < 8; ++kk) {
                const float w = pw[kk * HH];
                #pragma unroll
                for (int r = 0; r < 4; ++r)
                    acc[r] = fmaf(hq[r][kk], w, acc[r]);
            }
            pw += 8 * HH;
        }
        float bb = b2[c];
        #pragma unroll
        for (int r = 0; r < 4; ++r) {
            float v = __fadd_rn(acc[r], bb);
            h2f[(rbase + r) * HH + c] = v > 0.f ? v : 0.f;
        }
    }
    __syncthreads();

    // ---------- Phase 3: cs = sig(h2@W3+b3) * sig(g1@Wg2+bg2) (FROZEN) ----------
    {
        const int c = tid;
        float zi[TR], zg[TR];
        #pragma unroll
        for (int r = 0; r < TR; ++r) zi[r] = 0.f;
        {
            const float* __restrict__ pw = W3 + c;
            for (int k0 = 0; k0 < HH; k0 += 2) {
                float hq[TR][2];
                #pragma unroll
                for (int r = 0; r < TR; ++r)
                    *reinterpret_cast<float2*>(&hq[r][0]) =
                        *reinterpret_cast<const float2*>(&h2f[r * HH + k0]);
                #pragma unroll
                for (int kk = 0; kk < 2; ++kk) {
                    const float w = pw[kk * BD];
                    #pragma unroll
                    for (int r = 0; r < TR; ++r)
                        zi[r] = fmaf(hq[r][kk], w, zi[r]);
                }
                pw += 2 * BD;
            }
        }
        #pragma unroll
        for (int r = 0; r < TR; ++r) zg[r] = 0.f;
        {
            const float* __restrict__ pw = Wg2 + c;
            for (int k0 = 0; k0 < HH; k0 += 2) {
                float gq[TR][2];
                #pragma unroll
                for (int r = 0; r < TR; ++r)
                    *reinterpret_cast<float2*>(&gq[r][0]) =
                        *reinterpret_cast<const float2*>(&g1s[r][k0]);
                #pragma unroll
                for (int kk = 0; kk < 2; ++kk) {
                    const float w = pw[kk * BD];
                    #pragma unroll
                    for (int r = 0; r < TR; ++r)
                        zg[r] = fmaf(gq[r][kk], w, zg[r]);
                }
                pw += 2 * BD;
            }
        }
        __syncthreads();   // all h2 reads complete before cs is overwritten
        float bi = b3[c];
        float bq = bg2[c];
        #pragma unroll
        for (int r = 0; r < TR; ++r) {
            cs[r][c] = __fmul_rn(sig_xla(__fadd_rn(zi[r], bi)),
                                 sig_xla(__fadd_rn(zg[r], bq)));
        }
    }
    __syncthreads();

    // ---------- Phase 4: per-row top-K, exact on fp32 keys (FROZEN) ----------
    {
        const int lane = tid & 63;
        const int wv = tid >> 6;
        for (int rr = 0; rr < 2; ++rr) {
            const int r = wv + rr * 8;
            unsigned u[8];
            #pragma unroll
            for (int j = 0; j < 8; ++j)
                u[j] = __float_as_uint(cs[r][j * 64 + lane]);

            unsigned lo = 0u, hi = 0xffffffffu;
            while (lo < hi) {
                unsigned mid = lo + ((hi - lo) >> 1);
                int cnt = 0;
                #pragma unroll
                for (int j = 0; j < 8; ++j) cnt += (u[j] > mid) ? 1 : 0;
                cnt = wave_sum64(cnt);
                if (cnt < KSEL) hi = mid; else lo = mid + 1;
            }
            const unsigned T = lo;

            int ngt = 0, neq = 0;
            #pragma unroll
            for (int j = 0; j < 8; ++j) {
                ngt += (u[j] > T) ? 1 : 0;
                neq += (u[j] == T) ? 1 : 0;
            }
            ngt = wave_sum64(ngt);
            neq = wave_sum64(neq);
            const int m = KSEL - ngt;

            unsigned selbits = 0;
            #pragma unroll
            for (int j = 0; j < 8; ++j)
                if (u[j] > T) selbits |= (1u << j);

            if (neq == m) {
                #pragma unroll
                for (int j = 0; j < 8; ++j)
                    if (u[j] == T) selbits |= (1u << j);
            } else {
                int cnt8[8];
                #pragma unroll
                for (int j = 0; j < 8; ++j) cnt8[j] = 0;
                for (int jj = 0; jj < BD; ++jj) {
                    unsigned uj = __float_as_uint(cs[r][jj]);
                    if (uj == T) {
                        #pragma unroll
                        for (int j = 0; j < 8; ++j)
                            cnt8[j] += (u[j] == T && jj < (j * 64 + lane)) ? 1 : 0;
                    }
                }
                #pragma unroll
                for (int j = 0; j < 8; ++j)
                    if (u[j] == T && (ngt + cnt8[j]) < KSEL)
                        selbits |= (1u << j);
            }

            #pragma unroll
            for (int j = 0; j < 8; ++j)
                if (!(selbits & (1u << j))) xs[r][j * 64 + lane] = 0.0f;
        }
    }
    __syncthreads();

    // ---------- Phase R1 (MFMA): rs = relu(maskedX @ Wr1 + br1) ----------
    // M=16 N=128 K=512; wave w owns j-tile w (16 cols). 2-term bf16 split:
    // acc += Ah*Bh + Ah*Bl + Al*Bh (error ~1e-4, tolerance path, masks frozen).
    // A-frag: row=lane&15, k=(lane>>4)*8+s. B-frag: col=lane&15, same k.
    {
        const int lane = tid & 63;
        const int w = tid >> 6;
        const int arow = lane & 15;
        const int kb = (lane >> 4) * 8;
        const int j0 = w * 16;
        const int col = lane & 15;
        f32x4 acc = {0.f, 0.f, 0.f, 0.f};
        const float* __restrict__ pB = Wr1 + j0 + col;
        #pragma unroll 2
        for (int kt = 0; kt < 16; ++kt) {
            const int k0 = kt * 32 + kb;
            float av[8];
            *reinterpret_cast<float4*>(&av[0]) =
                *reinterpret_cast<const float4*>(&xs[arow][k0]);
            *reinterpret_cast<float4*>(&av[4]) =
                *reinterpret_cast<const float4*>(&xs[arow][k0 + 4]);
            bf16x8 ah, al;
            split8(av, ah, al);
            float bv[8];
            #pragma unroll
            for (int s = 0; s < 8; ++s) bv[s] = pB[(k0 + s) * HH];
            bf16x8 bh, bl;
            split8(bv, bh, bl);
            acc = __builtin_amdgcn_mfma_f32_16x16x32_bf16(ah, bh, acc, 0, 0, 0);
            acc = __builtin_amdgcn_mfma_f32_16x16x32_bf16(ah, bl, acc, 0, 0, 0);
            acc = __builtin_amdgcn_mfma_f32_16x16x32_bf16(al, bh, acc, 0, 0, 0);
        }
        float bias = br1[j0 + col];
        #pragma unroll
        for (int reg = 0; reg < 4; ++reg) {
            const int rr = (lane >> 4) * 4 + reg;
            float v = acc[reg] + bias;
            rs[rr][j0 + col] = v > 0.f ? v : 0.f;
        }
    }
    __syncthreads();

    // ---------- Phase R2 (MFMA): out = rs @ Wr2 + br2 ----------
    // M=16 N=358 (23 j-tiles, tail guarded) K=128.
    {
        const int lane = tid & 63;
        const int w = tid >> 6;
        const int arow = lane & 15;
        const int kb = (lane >> 4) * 8;
        const int col = lane & 15;
        for (int jt = w; jt < 23; jt += 8) {
            const int j0 = jt * 16;
            const int cc = j0 + col;
            const bool ok = (cc < KSEL);
            f32x4 acc = {0.f, 0.f, 0.f, 0.f};
            #pragma unroll
            for (int kt = 0; kt < 4; ++kt) {
                const int k0 = kt * 32 + kb;
                float av[8];
                *reinterpret_cast<float4*>(&av[0]) =
                    *reinterpret_cast<const float4*>(&rs[arow][k0]);
                *reinterpret_cast<float4*>(&av[4]) =
                    *reinterpret_cast<const float4*>(&rs[arow][k0 + 4]);
                bf16x8 ah, al;
                split8(av, ah, al);
                float bv[8];
                #pragma unroll
                for (int s = 0; s < 8; ++s)
                    bv[s] = ok ? Wr2[(k0 + s) * KSEL + cc] : 0.f;
                bf16x8 bh, bl;
                split8(bv, bh, bl);
                acc = __builtin_amdgcn_mfma_f32_16x16x32_bf16(ah, bh, acc, 0, 0, 0);
                acc = __builtin_amdgcn_mfma_f32_16x16x32_bf16(ah, bl, acc, 0, 0, 0);
                acc = __builtin_amdgcn_mfma_f32_16x16x32_bf16(al, bh, acc, 0, 0, 0);
            }
            if (ok) {
                float bias = br2[cc];
                #pragma unroll
                for (int reg = 0; reg < 4; ++reg) {
                    const int rr = (lane >> 4) * 4 + reg;
                    out[(row0 + rr) * KSEL + cc] = acc[reg] + bias;
                }
            }
        }
    }
}

extern "C" void kernel_launch(void* const* d_in, const int* in_sizes, int n_in,
                              void* d_out, int out_size, void* d_ws, size_t ws_size,
                              hipStream_t stream) {
    const float* x   = (const float*)d_in[0];
    const float* W1  = (const float*)d_in[1];
    const float* b1  = (const float*)d_in[2];
    const float* W2  = (const float*)d_in[3];
    const float* b2  = (const float*)d_in[4];
    const float* W3  = (const float*)d_in[5];
    const float* b3  = (const float*)d_in[6];
    const float* Wg1 = (const float*)d_in[7];
    const float* bg1 = (const float*)d_in[8];
    const float* Wg2 = (const float*)d_in[9];
    const float* bg2 = (const float*)d_in[10];
    const float* Wr1 = (const float*)d_in[11];
    const float* br1 = (const float*)d_in[12];
    const float* Wr2 = (const float*)d_in[13];
    const float* br2 = (const float*)d_in[14];
    float* out = (float*)d_out;

    const int nrows = in_sizes[0] / BD;          // 65536
    dim3 grid(nrows / TR), block(NT);
    afs_fused<<<grid, block, 0, stream>>>(x, W1, b1, W2, b2, W3, b3,
                                          Wg1, bg1, Wg2, bg2, Wr1, br1, Wr2, br2, out);
}

// Round 13
// 904.923 us; speedup vs baseline: 1.3691x; 1.0747x over previous
//
#include <hip/hip_runtime.h>
#include <math.h>

#define BD 512      // input dim D
#define HH 128      // hidden dim H
#define KSEL 358    // output dim K (top-k)
#define TR 16       // rows per block
#define NT 512      // threads per block (8 waves)
#define XP 4        // xs row pad (floats)
#define HP 4        // h1s row pad (floats)

typedef __attribute__((ext_vector_type(8))) short bf16x8;
typedef __attribute__((ext_vector_type(4))) float f32x4;

__device__ __forceinline__ int wave_sum64(int v) {
    #pragma unroll
    for (int off = 32; off > 0; off >>= 1) v += __shfl_xor(v, off, 64);
    return v;
}

// XLA:CPU / Eigen pexp-float (classic cephes) bit-emulation. FROZEN — this
// matches the grading reference bit-for-bit (round 5 PASS, absmax 0.0039,
// zero mask flips). Do not alter any operation or rounding mode here.
__device__ __forceinline__ float cephes_expf(float x) {
    x = fminf(x, 88.3762626647950f);
    x = fmaxf(x, -88.3762626647949f);
    float m = floorf(fmaf(x, 1.44269504088896341f, 0.5f));
    float r = __fsub_rn(x, __fmul_rn(m, 0.693359375f));
    r = __fsub_rn(r, __fmul_rn(m, -2.12194440e-4f));
    float r2 = __fmul_rn(r, r);
    float p = 1.9875691500E-4f;
    p = fmaf(p, r, 1.3981999507E-3f);
    p = fmaf(p, r, 8.3334519073E-3f);
    p = fmaf(p, r, 4.1665795894E-2f);
    p = fmaf(p, r, 1.6666665459E-1f);
    p = fmaf(p, r, 5.0000001201E-1f);
    float y = __fadd_rn(fmaf(p, r2, r), 1.0f);
    int mi = (int)m;
    y = __int_as_float(__float_as_int(y) + (mi << 23));
    return y;
}

__device__ __forceinline__ float sig_xla(float z) {
    float t = cephes_expf(-z);
    float d = __fadd_rn(1.0f, t);
    return __fdiv_rn(1.0f, d);
}

// Cheap truncation split: v = hi + lo + O(2^-16 rel). Tolerance path only
// (reconstruction MLP); masks never touch this.
__device__ __forceinline__ void split8t(const float* v, bf16x8& hi, bf16x8& lo) {
    #pragma unroll
    for (int s = 0; s < 8; ++s) {
        unsigned u = __float_as_uint(v[s]);
        float hf = __uint_as_float(u & 0xffff0000u);
        float res = v[s] - hf;                 // exact
        hi[s] = (short)(u >> 16);
        lo[s] = (short)(__float_as_uint(res) >> 16);
    }
}

__global__ __launch_bounds__(NT, 4)   // 4 waves/SIMD -> 2 blocks/CU, VGPR cap 128
void afs_fused(const float* __restrict__ x,
               const float* __restrict__ W1,  const float* __restrict__ b1,
               const float* __restrict__ W2,  const float* __restrict__ b2,
               const float* __restrict__ W3,  const float* __restrict__ b3,
               const float* __restrict__ Wg1, const float* __restrict__ bg1,
               const float* __restrict__ Wg2, const float* __restrict__ bg2,
               const float* __restrict__ Wr1, const float* __restrict__ br1,
               const float* __restrict__ Wr2, const float* __restrict__ br2,
               float* __restrict__ out)
{
    // 74240 B total -> 2 blocks/CU, 16 waves/CU.
    __shared__ float xs[TR][BD + XP];   // 33024 B; padded: MFMA row reads spread banks
    __shared__ float h1s[TR][HH + HP];  //  8448 B; h1 -> r (padded for MFMA reads)
    __shared__ float cs[TR][BD];        // 32768 B; h2[0..2048) + g1[2048..4096) -> scores

    float* h2f = &cs[0][0];             // h2[r][k] == h2f[r*HH+k]
    float* g1f = &cs[0][0] + TR * HH;   // g1[r][k] == g1f[r*HH+k]
    float (*rs)[HH + HP] = h1s;         // r overlaid on h1s (dead after phase 2)

    const int tid = threadIdx.x;
    const long long row0 = (long long)blockIdx.x * TR;

    // ---------- Phase 0: load x tile (row-wise, padded dest) ----------
    {
        #pragma unroll
        for (int i = tid; i < TR * (BD / 4); i += NT) {
            const int r = i >> 7;           // BD/4 = 128
            const int c4 = (i & 127) * 4;
            *reinterpret_cast<float4*>(&xs[r][c4]) =
                *reinterpret_cast<const float4*>(&x[(row0 + r) * BD + c4]);
        }
    }
    __syncthreads();

    // ---------- Phase 1: h1 = relu(x@W1+b1), g1 = relu(x@Wg1+bg1) (FROZEN) ----------
    {
        const int c = tid & (HH - 1);
        const int rbase = (tid >> 7) * 4;
        const float* __restrict__ pw1 = W1 + c;
        const float* __restrict__ pwg = Wg1 + c;
        float a1[4] = {0.f, 0.f, 0.f, 0.f};
        float ga[4] = {0.f, 0.f, 0.f, 0.f};
        for (int k0 = 0; k0 < BD; k0 += 8) {
            float xq[4][8];
            #pragma unroll
            for (int r = 0; r < 4; ++r) {
                *reinterpret_cast<float4*>(&xq[r][0]) =
                    *reinterpret_cast<const float4*>(&xs[rbase + r][k0]);
                *reinterpret_cast<float4*>(&xq[r][4]) =
                    *reinterpret_cast<const float4*>(&xs[rbase + r][k0 + 4]);
            }
            #pragma unroll
            for (int kk = 0; kk < 8; ++kk) {
                const float w1 = pw1[kk * HH];
                const float wg = pwg[kk * HH];
                #pragma unroll
                for (int r = 0; r < 4; ++r) {
                    a1[r] = fmaf(xq[r][kk], w1, a1[r]);
                    ga[r] = fmaf(xq[r][kk], wg, ga[r]);
                }
            }
            pw1 += 8 * HH;
            pwg += 8 * HH;
        }
        float bb1 = b1[c], bbg = bg1[c];
        #pragma unroll
        for (int r = 0; r < 4; ++r) {
            float v1 = __fadd_rn(a1[r], bb1);
            float vg = __fadd_rn(ga[r], bbg);
            h1s[rbase + r][c] = v1 > 0.f ? v1 : 0.f;
            g1f[(rbase + r) * HH + c] = vg > 0.f ? vg : 0.f;
        }
    }
    __syncthreads();

    // ---------- Phase 2: h2 = relu(h1@W2+b2), into cs-overlay (FROZEN) ----------
    {
        const int c = tid & (HH - 1);
        const int rbase = (tid >> 7) * 4;
        const float* __restrict__ pw = W2 + c;
        float acc[4] = {0.f, 0.f, 0.f, 0.f};
        for (int k0 = 0; k0 < HH; k0 += 8) {
            float hq[4][8];
            #pragma unroll
            for (int r = 0; r < 4; ++r) {
                *reinterpret_cast<float4*>(&hq[r][0]) =
                    *reinterpret_cast<const float4*>(&h1s[rbase + r][k0]);
                *reinterpret_cast<float4*>(&hq[r][4]) =
                    *reinterpret_cast<const float4*>(&h1s[rbase + r][k0 + 4]);
            }
            #pragma unroll
            for (int kk = 0; kk < 8; ++kk) {
                const float w = pw[kk * HH];
                #pragma unroll
                for (int r = 0; r < 4; ++r)
                    acc[r] = fmaf(hq[r][kk], w, acc[r]);
            }
            pw += 8 * HH;
        }
        float bb = b2[c];
        #pragma unroll
        for (int r = 0; r < 4; ++r) {
            float v = __fadd_rn(acc[r], bb);
            h2f[(rbase + r) * HH + c] = v > 0.f ? v : 0.f;
        }
    }
    __syncthreads();

    // ---------- Phase 3: cs = sig(h2@W3+b3) * sig(g1@Wg2+bg2) (FROZEN) ----------
    {
        const int c = tid;
        float zi[TR], zg[TR];
        #pragma unroll
        for (int r = 0; r < TR; ++r) zi[r] = 0.f;
        {
            const float* __restrict__ pw = W3 + c;
            for (int k0 = 0; k0 < HH; k0 += 2) {
                float hq[TR][2];
                #pragma unroll
                for (int r = 0; r < TR; ++r)
                    *reinterpret_cast<float2*>(&hq[r][0]) =
                        *reinterpret_cast<const float2*>(&h2f[r * HH + k0]);
                #pragma unroll
                for (int kk = 0; kk < 2; ++kk) {
                    const float w = pw[kk * BD];
                    #pragma unroll
                    for (int r = 0; r < TR; ++r)
                        zi[r] = fmaf(hq[r][kk], w, zi[r]);
                }
                pw += 2 * BD;
            }
        }
        #pragma unroll
        for (int r = 0; r < TR; ++r) zg[r] = 0.f;
        {
            const float* __restrict__ pw = Wg2 + c;
            for (int k0 = 0; k0 < HH; k0 += 2) {
                float gq[TR][2];
                #pragma unroll
                for (int r = 0; r < TR; ++r)
                    *reinterpret_cast<float2*>(&gq[r][0]) =
                        *reinterpret_cast<const float2*>(&g1f[r * HH + k0]);
                #pragma unroll
                for (int kk = 0; kk < 2; ++kk) {
                    const float w = pw[kk * BD];
                    #pragma unroll
                    for (int r = 0; r < TR; ++r)
                        zg[r] = fmaf(gq[r][kk], w, zg[r]);
                }
                pw += 2 * BD;
            }
        }
        __syncthreads();   // all h2/g1 reads complete before cs is overwritten
        float bi = b3[c];
        float bq = bg2[c];
        #pragma unroll
        for (int r = 0; r < TR; ++r) {
            cs[r][c] = __fmul_rn(sig_xla(__fadd_rn(zi[r], bi)),
                                 sig_xla(__fadd_rn(zg[r], bq)));
        }
    }
    __syncthreads();

    // ---------- Phase 4: per-row top-K, exact on fp32 keys (FROZEN) ----------
    {
        const int lane = tid & 63;
        const int wv = tid >> 6;
        for (int rr = 0; rr < 2; ++rr) {
            const int r = wv + rr * 8;
            unsigned u[8];
            #pragma unroll
            for (int j = 0; j < 8; ++j)
                u[j] = __float_as_uint(cs[r][j * 64 + lane]);

            unsigned lo = 0u, hi = 0xffffffffu;
            while (lo < hi) {
                unsigned mid = lo + ((hi - lo) >> 1);
                int cnt = 0;
                #pragma unroll
                for (int j = 0; j < 8; ++j) cnt += (u[j] > mid) ? 1 : 0;
                cnt = wave_sum64(cnt);
                if (cnt < KSEL) hi = mid; else lo = mid + 1;
            }
            const unsigned T = lo;

            int ngt = 0, neq = 0;
            #pragma unroll
            for (int j = 0; j < 8; ++j) {
                ngt += (u[j] > T) ? 1 : 0;
                neq += (u[j] == T) ? 1 : 0;
            }
            ngt = wave_sum64(ngt);
            neq = wave_sum64(neq);
            const int m = KSEL - ngt;

            unsigned selbits = 0;
            #pragma unroll
            for (int j = 0; j < 8; ++j)
                if (u[j] > T) selbits |= (1u << j);

            if (neq == m) {
                #pragma unroll
                for (int j = 0; j < 8; ++j)
                    if (u[j] == T) selbits |= (1u << j);
            } else {
                int cnt8[8];
                #pragma unroll
                for (int j = 0; j < 8; ++j) cnt8[j] = 0;
                for (int jj = 0; jj < BD; ++jj) {
                    unsigned uj = __float_as_uint(cs[r][jj]);
                    if (uj == T) {
                        #pragma unroll
                        for (int j = 0; j < 8; ++j)
                            cnt8[j] += (u[j] == T && jj < (j * 64 + lane)) ? 1 : 0;
                    }
                }
                #pragma unroll
                for (int j = 0; j < 8; ++j)
                    if (u[j] == T && (ngt + cnt8[j]) < KSEL)
                        selbits |= (1u << j);
            }

            #pragma unroll
            for (int j = 0; j < 8; ++j)
                if (!(selbits & (1u << j))) xs[r][j * 64 + lane] = 0.0f;
        }
    }
    __syncthreads();

    // ---------- Phase R1 (MFMA): rs = relu(maskedX @ Wr1 + br1) ----------
    // M=16 N=128 K=512; wave w owns 16 cols. 3-term bf16 split (tolerance path).
    {
        const int lane = tid & 63;
        const int w = tid >> 6;
        const int arow = lane & 15;
        const int kb = (lane >> 4) * 8;
        const int j0 = w * 16;
        const int col = lane & 15;
        f32x4 acc = {0.f, 0.f, 0.f, 0.f};
        const float* __restrict__ pB = Wr1 + j0 + col;
        #pragma unroll 2
        for (int kt = 0; kt < 16; ++kt) {
            const int k0 = kt * 32 + kb;
            float av[8];
            *reinterpret_cast<float4*>(&av[0]) =
                *reinterpret_cast<const float4*>(&xs[arow][k0]);
            *reinterpret_cast<float4*>(&av[4]) =
                *reinterpret_cast<const float4*>(&xs[arow][k0 + 4]);
            bf16x8 ah, al;
            split8t(av, ah, al);
            float bv[8];
            #pragma unroll
            for (int s = 0; s < 8; ++s) bv[s] = pB[(k0 + s) * HH];
            bf16x8 bh, bl;
            split8t(bv, bh, bl);
            acc = __builtin_amdgcn_mfma_f32_16x16x32_bf16(ah, bh, acc, 0, 0, 0);
            acc = __builtin_amdgcn_mfma_f32_16x16x32_bf16(ah, bl, acc, 0, 0, 0);
            acc = __builtin_amdgcn_mfma_f32_16x16x32_bf16(al, bh, acc, 0, 0, 0);
        }
        float bias = br1[j0 + col];
        #pragma unroll
        for (int reg = 0; reg < 4; ++reg) {
            const int rr = (lane >> 4) * 4 + reg;
            float v = acc[reg] + bias;
            rs[rr][j0 + col] = v > 0.f ? v : 0.f;
        }
    }
    __syncthreads();

    // ---------- Phase R2 (MFMA): out = rs @ Wr2 + br2 ----------
    // M=16 N=358 (23 j-tiles, tail guarded) K=128. A-fragments split ONCE.
    {
        const int lane = tid & 63;
        const int w = tid >> 6;
        const int arow = lane & 15;
        const int kb = (lane >> 4) * 8;
        const int col = lane & 15;
        bf16x8 ah[4], al[4];
        #pragma unroll
        for (int kt = 0; kt < 4; ++kt) {
            const int k0 = kt * 32 + kb;
            float av[8];
            *reinterpret_cast<float4*>(&av[0]) =
                *reinterpret_cast<const float4*>(&rs[arow][k0]);
            *reinterpret_cast<float4*>(&av[4]) =
                *reinterpret_cast<const float4*>(&rs[arow][k0 + 4]);
            split8t(av, ah[kt], al[kt]);
        }
        for (int jt = w; jt < 23; jt += 8) {
            const int j0 = jt * 16;
            const int cc = j0 + col;
            const bool ok = (cc < KSEL);
            f32x4 acc = {0.f, 0.f, 0.f, 0.f};
            #pragma unroll
            for (int kt = 0; kt < 4; ++kt) {
                const int k0 = kt * 32 + kb;
                float bv[8];
                #pragma unroll
                for (int s = 0; s < 8; ++s)
                    bv[s] = ok ? Wr2[(k0 + s) * KSEL + cc] : 0.f;
                bf16x8 bh, bl;
                split8t(bv, bh, bl);
                acc = __builtin_amdgcn_mfma_f32_16x16x32_bf16(ah[kt], bh, acc, 0, 0, 0);
                acc = __builtin_amdgcn_mfma_f32_16x16x32_bf16(ah[kt], bl, acc, 0, 0, 0);
                acc = __builtin_amdgcn_mfma_f32_16x16x32_bf16(al[kt], bh, acc, 0, 0, 0);
            }
            if (ok) {
                float bias = br2[cc];
                #pragma unroll
                for (int reg = 0; reg < 4; ++reg) {
                    const int rr = (lane >> 4) * 4 + reg;
                    out[(row0 + rr) * KSEL + cc] = acc[reg] + bias;
                }
            }
        }
    }
}

extern "C" void kernel_launch(void* const* d_in, const int* in_sizes, int n_in,
                              void* d_out, int out_size, void* d_ws, size_t ws_size,
                              hipStream_t stream) {
    const float* x   = (const float*)d_in[0];
    const float* W1  = (const float*)d_in[1];
    const float* b1  = (const float*)d_in[2];
    const float* W2  = (const float*)d_in[3];
    const float* b2  = (const float*)d_in[4];
    const float* W3  = (const float*)d_in[5];
    const float* b3  = (const float*)d_in[6];
    const float* Wg1 = (const float*)d_in[7];
    const float* bg1 = (const float*)d_in[8];
    const float* Wg2 = (const float*)d_in[9];
    const float* bg2 = (const float*)d_in[10];
    const float* Wr1 = (const float*)d_in[11];
    const float* br1 = (const float*)d_in[12];
    const float* Wr2 = (const float*)d_in[13];
    const float* br2 = (const float*)d_in[14];
    float* out = (float*)d_out;

    const int nrows = in_sizes[0] / BD;          // 65536
    dim3 grid(nrows / TR), block(NT);
    afs_fused<<<grid, block, 0, stream>>>(x, W1, b1, W2, b2, W3, b3,
                                          Wg1, bg1, Wg2, bg2, Wr1, br1, Wr2, br2, out);
}